// Round 15
// baseline (200.092 us; speedup 1.0000x reference)
//
#include <hip/hip_runtime.h>
#include <math.h>

#define N_NODES 50000
#define N_EDGES 800000
#define NPART 8
#define PART_SZ ((N_NODES + NPART - 1) / NPART)   // 6250
#define CAP 64                                    // per-node bucket capacity
#define FC1_BLOCKS 784                            // 3136 wave-tiles >= 3125
#define SCAT_BLOCKS 2048                          // 8 parts x 256 blocks

typedef __attribute__((ext_vector_type(8))) short short8;
typedef __attribute__((ext_vector_type(8))) unsigned short ushort8;
typedef __attribute__((ext_vector_type(4))) float v4f;
typedef __attribute__((ext_vector_type(2))) float v2f;
typedef __attribute__((ext_vector_type(4))) int int4v;

// ---- bf16 helpers (raw ushort storage) ----
__device__ __forceinline__ float bf2f(unsigned short h) {
    return __uint_as_float(((unsigned int)h) << 16);
}
__device__ __forceinline__ unsigned short f2bf(float f) {
    unsigned int u = __float_as_uint(f);
    u += 0x7fff + ((u >> 16) & 1);          // round-to-nearest-even
    return (unsigned short)(u >> 16);
}

// A-fragment load from fp32 matrix: lane row m, k = kc*32 + quad*8 + j
__device__ __forceinline__ short8 load_afrag(const float* X, size_t row, int K,
                                             int kc, int quad) {
    const float* p = X + row * K + kc * 32 + quad * 8;
    const float4 t0 = *(const float4*)p;
    const float4 t1 = *(const float4*)(p + 4);
    short8 a;
    a[0] = (short)f2bf(t0.x); a[1] = (short)f2bf(t0.y);
    a[2] = (short)f2bf(t0.z); a[3] = (short)f2bf(t0.w);
    a[4] = (short)f2bf(t1.x); a[5] = (short)f2bf(t1.y);
    a[6] = (short)f2bf(t1.z); a[7] = (short)f2bf(t1.w);
    return a;
}

// B-fragments straight from global (no LDS): W row-major [64][K], L2-broadcast.
template <int K>
__device__ __forceinline__ void load_wfrags(const float* __restrict__ W,
                                            int d, int quad, short8 wf[4][K / 32]) {
#pragma unroll
    for (int ng = 0; ng < 4; ++ng) {
#pragma unroll
        for (int kc = 0; kc < K / 32; ++kc) {
            const float* wp = W + (size_t)(ng * 16 + d) * K + kc * 32 + quad * 8;
            const float4 w0 = *(const float4*)wp;
            const float4 w1 = *(const float4*)(wp + 4);
            short8 f;
            f[0] = (short)f2bf(w0.x); f[1] = (short)f2bf(w0.y);
            f[2] = (short)f2bf(w0.z); f[3] = (short)f2bf(w0.w);
            f[4] = (short)f2bf(w1.x); f[5] = (short)f2bf(w1.y);
            f[6] = (short)f2bf(w1.z); f[7] = (short)f2bf(w1.w);
            wf[ng][kc] = f;
        }
    }
}

// ---------------------------------------------------------------------------
// fc body, LDS-free: one wave per 16-node tile.
// ---------------------------------------------------------------------------
template <int K>
__device__ __forceinline__ void fc_body_nolds(
    const float* __restrict__ X, const float* __restrict__ W,
    const float* __restrict__ al, const float* __restrict__ ar,
    unsigned short* __restrict__ Hout, float* __restrict__ el,
    float* __restrict__ er, int tile, int nTiles, int lane)
{
    if (tile >= nTiles) return;
    const int d = lane & 15;
    const int quad = lane >> 4;
    short8 wf[4][K / 32];
    load_wfrags<K>(W, d, quad, wf);
    const int node0 = tile * 16;
    v4f cc[4] = {{0.f,0.f,0.f,0.f},{0.f,0.f,0.f,0.f},{0.f,0.f,0.f,0.f},{0.f,0.f,0.f,0.f}};
#pragma unroll
    for (int kc = 0; kc < K / 32; ++kc) {
        const short8 a = load_afrag(X, (size_t)(node0 + d), K, kc, quad);
        cc[0] = __builtin_amdgcn_mfma_f32_16x16x32_bf16(a, wf[0][kc], cc[0], 0, 0, 0);
        cc[1] = __builtin_amdgcn_mfma_f32_16x16x32_bf16(a, wf[1][kc], cc[1], 0, 0, 0);
        cc[2] = __builtin_amdgcn_mfma_f32_16x16x32_bf16(a, wf[2][kc], cc[2], 0, 0, 0);
        cc[3] = __builtin_amdgcn_mfma_f32_16x16x32_bf16(a, wf[3][kc], cc[3], 0, 0, 0);
    }
#pragma unroll
    for (int ng = 0; ng < 4; ++ng) {
        const float alv = al[ng * 16 + d];
        const float arv = ar[ng * 16 + d];
        const v4f c = cc[ng];
#pragma unroll
        for (int r = 0; r < 4; ++r) {
            const int node = node0 + quad * 4 + r;
            Hout[(size_t)node * 64 + ng * 16 + d] = f2bf(c[r]);
            float vel = c[r] * alv;
            float ver = c[r] * arv;
#pragma unroll
            for (int off = 1; off < 16; off <<= 1) {
                vel += __shfl_xor(vel, off);
                ver += __shfl_xor(ver, off);
            }
            if (d == 0) {
                el[node * 4 + ng] = vel;
                er[node * 4 + ng] = ver;
            }
        }
    }
}

// ---------------------------------------------------------------------------
// Scatter body (R14): padded counters cnt16[d*16], unroll-8 int4 NT loads.
// ---------------------------------------------------------------------------
__device__ __forceinline__ void scat1(int d, int s, int lo, int hi,
                                      int* __restrict__ cnt16,
                                      unsigned short* __restrict__ col)
{
    if (d >= lo && d < hi) {
        const int pos = atomicAdd(&cnt16[(unsigned)d * 16], 1);
        if (pos < CAP) col[(unsigned)d * CAP + pos] = (unsigned short)s;
    }
}

__device__ __forceinline__ void scatter_body(
    const int* __restrict__ src, const int* __restrict__ dst,
    int* __restrict__ cnt16, unsigned short* __restrict__ col,
    int part, int sblk)
{
    const int lo = part * PART_SZ;
    const int hi = lo + PART_SZ;
    const int tid_p = sblk * 256 + (int)threadIdx.x;               // 0..65535
    const int stride = (SCAT_BLOCKS / NPART) * 256;                // 65536
    const int4v* dst4 = (const int4v*)dst;
    const int4v* src4 = (const int4v*)src;
    const int NQ = N_EDGES / 4;                                    // 200000
    for (int q = tid_p; q < NQ; q += 2 * stride) {
        const int q2 = q + stride;
        const bool ok2 = q2 < NQ;
        const int4v dA = __builtin_nontemporal_load(dst4 + q);
        const int4v sA = __builtin_nontemporal_load(src4 + q);
        const int4v dB = ok2 ? __builtin_nontemporal_load(dst4 + q2) : (int4v){-1,-1,-1,-1};
        const int4v sB = ok2 ? __builtin_nontemporal_load(src4 + q2) : (int4v){0,0,0,0};
        scat1(dA[0], sA[0], lo, hi, cnt16, col);
        scat1(dA[1], sA[1], lo, hi, cnt16, col);
        scat1(dA[2], sA[2], lo, hi, cnt16, col);
        scat1(dA[3], sA[3], lo, hi, cnt16, col);
        scat1(dB[0], sB[0], lo, hi, cnt16, col);
        scat1(dB[1], sB[1], lo, hi, cnt16, col);
        scat1(dB[2], sB[2], lo, hi, cnt16, col);
        scat1(dB[3], sB[3], lo, hi, cnt16, col);
    }
}

// ---------------------------------------------------------------------------
// Fused dispatch 1: blocks [0,784) fc1 (LDS-free MFMA), blocks [784,2832)
// bucket scatter. Independent data; scatter's latency hides under fc1.
// ---------------------------------------------------------------------------
__global__ __launch_bounds__(256) void fc1_scatter_fused(
    const float* __restrict__ feat, const float* __restrict__ W1,
    const float* __restrict__ al1, const float* __restrict__ ar1,
    unsigned short* __restrict__ A, float* __restrict__ el1,
    float* __restrict__ er1, int nTiles,
    const int* __restrict__ src, const int* __restrict__ dst,
    int* __restrict__ cnt16, unsigned short* __restrict__ col)
{
    if ((int)blockIdx.x < FC1_BLOCKS) {
        const int tile = blockIdx.x * 4 + (threadIdx.x >> 6);
        fc_body_nolds<128>(feat, W1, al1, ar1, A, el1, er1, tile, nTiles,
                           threadIdx.x & 63);
    } else {
        const int part = blockIdx.x & (NPART - 1);            // 784 % 8 == 0
        const int sblk = ((int)blockIdx.x - FC1_BLOCKS) >> 3; // 0..255
        scatter_body(src, dst, cnt16, col, part, sblk);
    }
}

// ---------------------------------------------------------------------------
// Lane-pair agg walk (R14): one wave = 2 nodes (halves); lane hl covers a
// bf16 column pair via one u32 gather; 16-edge iters, dual 8-wide predication.
// ---------------------------------------------------------------------------
__device__ __forceinline__ void agg_walk_pair(
    const unsigned short* __restrict__ colrow, int len, int len_max,
    const float* __restrict__ el, const unsigned int* __restrict__ Hf32,
    int hb, int hl, float erv_a,
    float& accL_out, float& accH_out, float& sacc_a_out)
{
    const int j_a = hl >> 2;
    const unsigned h_a = (unsigned)(hl & 3);
    const int hd = hl >> 3;
    float accL0 = 0.f, accL1 = 0.f, accH0 = 0.f, accH1 = 0.f;
    float sacc_a = 0.f;
    for (int i = 0; i < len_max; i += 16) {
        const ushort8 sv0 = __builtin_nontemporal_load((const ushort8*)(colrow + i));
        const ushort8 sv1 = __builtin_nontemporal_load((const ushort8*)(colrow + i + 8));
        const int rm = len - i;
        const unsigned sa0 = (unsigned)colrow[i + j_a];
        const unsigned sa1 = (unsigned)colrow[i + 8 + j_a];
        float x0 = el[sa0 * 4u + h_a] + erv_a;
        float x1 = el[sa1 * 4u + h_a] + erv_a;
        x0 = fmaxf(x0, 0.2f * x0);
        x1 = fmaxf(x1, 0.2f * x1);
        float a0 = __expf(x0);
        float a1 = __expf(x1);
        a0 = (j_a < rm) ? a0 : 0.f;
        a1 = (j_a + 8 < rm) ? a1 : 0.f;
        sacc_a += a0 + a1;
        unsigned uu[16];
#pragma unroll
        for (int j = 0; j < 8; ++j)
            uu[j] = Hf32[(unsigned)sv0[j] * 32u + (unsigned)hl];
#pragma unroll
        for (int j = 0; j < 8; ++j)
            uu[8 + j] = Hf32[(unsigned)sv1[j] * 32u + (unsigned)hl];
#pragma unroll
        for (int j = 0; j < 8; ++j) {
            const float aj = __shfl(a0, hb + j * 4 + hd);
            const float lo = __uint_as_float(uu[j] << 16);
            const float hi = __uint_as_float(uu[j] & 0xffff0000u);
            if (j & 1) { accL1 = fmaf(aj, lo, accL1); accH1 = fmaf(aj, hi, accH1); }
            else       { accL0 = fmaf(aj, lo, accL0); accH0 = fmaf(aj, hi, accH0); }
        }
#pragma unroll
        for (int j = 0; j < 8; ++j) {
            const float aj = __shfl(a1, hb + j * 4 + hd);
            const float lo = __uint_as_float(uu[8 + j] << 16);
            const float hi = __uint_as_float(uu[8 + j] & 0xffff0000u);
            if (j & 1) { accL1 = fmaf(aj, lo, accL1); accH1 = fmaf(aj, hi, accH1); }
            else       { accL0 = fmaf(aj, lo, accL0); accH0 = fmaf(aj, hi, accH0); }
        }
    }
    sacc_a += __shfl_xor(sacc_a, 4);
    sacc_a += __shfl_xor(sacc_a, 8);
    sacc_a += __shfl_xor(sacc_a, 16);
    sacc_a_out = sacc_a;
    accL_out = accL0 + accL1;
    accH_out = accH0 + accH1;
}

// ---------------------------------------------------------------------------
// Fused dispatch 2: agg_relu + fc2. One wave per 16-node tile: 8 pair-walks
// produce h2 = relu(agg/s + b1) into a padded LDS tile (stride 72 shorts ->
// conflict-free both directions), then MFMA h2 @ W2^T from LDS fragments.
// el2/er2/C are fresh buffers (no race with el1/er1/A read by agg phase).
// ---------------------------------------------------------------------------
__global__ __launch_bounds__(256) void agg_fc2_fused(
    const int* __restrict__ cnt16, const unsigned short* __restrict__ col,
    const float* __restrict__ el1, const float* __restrict__ er1,
    const unsigned int* __restrict__ A32, const float* __restrict__ b1,
    const float* __restrict__ W2, const float* __restrict__ al2,
    const float* __restrict__ ar2, unsigned short* __restrict__ C,
    float* __restrict__ el2, float* __restrict__ er2, int nTiles)
{
    __shared__ unsigned short hs[4][16][72];
    const int lane = threadIdx.x & 63;
    const int wave = threadIdx.x >> 6;
    const int tile = blockIdx.x * 4 + wave;
    const bool valid = tile < nTiles;
    const int hl = lane & 31;
    const int hb = lane & 32;
    const int hd = hl >> 3;
    const int cg = hd * 16 + (hl & 7) * 2;

    if (valid) {
#pragma unroll 1
        for (int r = 0; r < 8; ++r) {
            const int node = tile * 16 + 2 * r + (lane >> 5);
            const float erv_a = el1 == er1 ? 0.f : er1[node * 4 + (hl & 3)];
            const int len = min(cnt16[(unsigned)node * 16], CAP);
            const int len_max = max(len, __shfl_xor(len, 32));
            float accL, accH, sacc_a;
            agg_walk_pair(col + (unsigned)node * CAP, len, len_max, el1, A32,
                          hb, hl, erv_a, accL, accH, sacc_a);
            const float sc = __shfl(sacc_a, hb + hd);
            float vL = sc > 0.f ? accL / sc : 0.f;
            float vH = sc > 0.f ? accH / sc : 0.f;
            vL += b1[cg];   vH += b1[cg + 1];
            vL = fmaxf(vL, 0.f);
            vH = fmaxf(vH, 0.f);
            const unsigned u = (unsigned)f2bf(vL) | ((unsigned)f2bf(vH) << 16);
            *(unsigned int*)&hs[wave][2 * r + (lane >> 5)][cg] = u;
        }
    }
    __syncthreads();
    if (valid) {
        const int d = lane & 15;
        const int quad = lane >> 4;
        short8 wf[4][2];
        load_wfrags<64>(W2, d, quad, wf);
        v4f cc[4] = {{0.f,0.f,0.f,0.f},{0.f,0.f,0.f,0.f},{0.f,0.f,0.f,0.f},{0.f,0.f,0.f,0.f}};
#pragma unroll
        for (int kc = 0; kc < 2; ++kc) {
            const short8 a = *(const short8*)&hs[wave][d][kc * 32 + quad * 8];
            cc[0] = __builtin_amdgcn_mfma_f32_16x16x32_bf16(a, wf[0][kc], cc[0], 0, 0, 0);
            cc[1] = __builtin_amdgcn_mfma_f32_16x16x32_bf16(a, wf[1][kc], cc[1], 0, 0, 0);
            cc[2] = __builtin_amdgcn_mfma_f32_16x16x32_bf16(a, wf[2][kc], cc[2], 0, 0, 0);
            cc[3] = __builtin_amdgcn_mfma_f32_16x16x32_bf16(a, wf[3][kc], cc[3], 0, 0, 0);
        }
        const int node0 = tile * 16;
#pragma unroll
        for (int ng = 0; ng < 4; ++ng) {
            const float alv = al2[ng * 16 + d];
            const float arv = ar2[ng * 16 + d];
            const v4f c = cc[ng];
#pragma unroll
            for (int r = 0; r < 4; ++r) {
                const int node = node0 + quad * 4 + r;
                C[(size_t)node * 64 + ng * 16 + d] = f2bf(c[r]);
                float vel = c[r] * alv;
                float ver = c[r] * arv;
#pragma unroll
                for (int off = 1; off < 16; off <<= 1) {
                    vel += __shfl_xor(vel, off);
                    ver += __shfl_xor(ver, off);
                }
                if (d == 0) {
                    el2[node * 4 + ng] = vel;
                    er2[node * 4 + ng] = ver;
                }
            }
        }
    }
}

// ---------------------------------------------------------------------------
// Final aggregation (R14): 2 nodes/wave, head-mean (+b2), 16-dim log-softmax.
// ---------------------------------------------------------------------------
__global__ __launch_bounds__(256) void agg_final_kernel(
    const int* __restrict__ cnt16, const unsigned short* __restrict__ col,
    const float* __restrict__ el, const float* __restrict__ er,
    const unsigned int* __restrict__ Hf32, const float* __restrict__ b,
    float* __restrict__ out, int n)
{
    const int lane = threadIdx.x & 63;
    const int wave = threadIdx.x >> 6;
    const int hl = lane & 31;
    const int hb = lane & 32;
    const int node = blockIdx.x * 8 + wave * 2 + (lane >> 5);
    if (node >= n) return;
    const int hd = hl >> 3;
    const int cg = hd * 16 + (hl & 7) * 2;
    const float erv_a = er[node * 4 + (hl & 3)];
    const int len = min(cnt16[(unsigned)node * 16], CAP);
    const int len_max = max(len, __shfl_xor(len, 32));
    float accL, accH, sacc_a;
    agg_walk_pair(col + (unsigned)node * CAP, len, len_max, el, Hf32,
                  hb, hl, erv_a, accL, accH, sacc_a);
    const float sc = __shfl(sacc_a, hb + hd);
    float zL = sc > 0.f ? accL / sc : 0.f;
    float zH = sc > 0.f ? accH / sc : 0.f;
    zL += b[cg];   zH += b[cg + 1];
    zL += __shfl_xor(zL, 8);  zL += __shfl_xor(zL, 16);  zL *= 0.25f;
    zH += __shfl_xor(zH, 8);  zH += __shfl_xor(zH, 16);  zH *= 0.25f;
    float m = fmaxf(zL, zH);
    m = fmaxf(m, __shfl_xor(m, 1));
    m = fmaxf(m, __shfl_xor(m, 2));
    m = fmaxf(m, __shfl_xor(m, 4));
    float se = __expf(zL - m) + __expf(zH - m);
    se += __shfl_xor(se, 1);
    se += __shfl_xor(se, 2);
    se += __shfl_xor(se, 4);
    const float lse = __logf(se);
    if (hl < 8) {
        v2f r;
        r[0] = zL - m - lse;
        r[1] = zH - m - lse;
        __builtin_nontemporal_store(r, (v2f*)(out + (size_t)node * 16 + hl * 2));
    }
}

extern "C" void kernel_launch(void* const* d_in, const int* in_sizes, int n_in,
                              void* d_out, int out_size, void* d_ws, size_t ws_size,
                              hipStream_t stream)
{
    const float* feat = (const float*)d_in[0];
    const int*   src  = (const int*)d_in[1];
    const int*   dst  = (const int*)d_in[2];
    const float* W1   = (const float*)d_in[3];
    const float* al1  = (const float*)d_in[4];
    const float* ar1  = (const float*)d_in[5];
    const float* b1   = (const float*)d_in[6];
    const float* W2   = (const float*)d_in[7];
    const float* al2  = (const float*)d_in[8];
    const float* ar2  = (const float*)d_in[9];
    const float* b2   = (const float*)d_in[10];
    float* out = (float*)d_out;

    float* el1 = (float*)d_ws;                                // [N,4]
    float* er1 = el1 + N_NODES * 4;
    float* el2 = er1 + N_NODES * 4;
    float* er2 = el2 + N_NODES * 4;
    int*   cnt16 = (int*)(er2 + N_NODES * 4);                 // [N*16] padded
    uintptr_t p = ((uintptr_t)(cnt16 + N_NODES * 16) + 15) & ~(uintptr_t)15;
    unsigned short* col = (unsigned short*)p;                 // [N*CAP + 64]
    unsigned short* A   = col + (size_t)N_NODES * CAP + 64;   // h1 [N,64] bf16
    unsigned short* C   = A + (size_t)N_NODES * 64;           // h2' [N,64] bf16

    const int NT = N_NODES / 16;                    // 3125 tiles (exact)
    const int FB = (NT + 3) / 4;                    // 782 blocks
    const int AB2 = (N_NODES + 7) / 8;              // 6250 agg blocks

    // 1) zero cnt16 + col (col zeroing makes tail gathers hit row 0)
    (void)hipMemsetAsync(cnt16, 0, (size_t)((char*)A - (char*)cnt16), stream);

    // 2) fc1 || bucket-scatter (independent; LDS-free fc keeps occupancy high)
    fc1_scatter_fused<<<FC1_BLOCKS + SCAT_BLOCKS, 256, 0, stream>>>(
        feat, W1, al1, ar1, A, el1, er1, NT, src, dst, cnt16, col);

    // 3) agg_relu + fc2 fused per 16-node tile (LDS bounce, no B round-trip)
    agg_fc2_fused<<<FB, 256, 0, stream>>>(cnt16, col, el1, er1,
                                          (const unsigned int*)A, b1,
                                          W2, al2, ar2, C, el2, er2, NT);

    // 4) final aggregation + head-mean + log-softmax
    agg_final_kernel<<<AB2, 256, 0, stream>>>(cnt16, col, el2, er2,
                                              (const unsigned int*)C, b2, out, N_NODES);
}